// Round 13
// baseline (349.006 us; speedup 1.0000x reference)
//
#include <hip/hip_runtime.h>
#include <hip/hip_fp16.h>
#include <math.h>

#define NUM_USERS 100000
#define NUM_ITEMS 50000
#define N_NODES   150000   // NUM_USERS + NUM_ITEMS
#define N_EDGES   2400000
#define HALF_E    (N_EDGES / 2)
#define EMB       64
#define BATCH     4096
#define TAU        0.2f
#define SSL_LAMBDA 0.1f
#define REG_LAMBDA 1e-4f

// ---- binned CSR build (coarse 512-row buckets; R7/R8 write-amp model) ----
// R13: BINA_BLK 512->1024. L = 2.4M/(B*NB) = 8 records/run (64B): arena write
// amp ~3 (58 MB) but 2x wave parallelism — the phase runs at 30% of BW, so
// latency hiding wins (R12: VALUBusy 2.9%, occ 30%).
#define NB        293           // 293*512 = 150016 >= N_NODES
#define BROWS     512
#define CAP       13632         // item-bucket mean 12288 + 12 sigma
#define BINA_BLK  1024
#define CAST_BLK  9375          // 150000*64/4 threads / 256

// ---------- helpers ----------
__device__ __forceinline__ float wave_sum(float v) {
    #pragma unroll
    for (int m = 1; m < 64; m <<= 1) v += __shfl_xor(v, m, 64);
    return v;
}
__device__ __forceinline__ __half2 bits2h2(int b) {
    union { int i; __half2 h; } u; u.i = b; return u.h;
}
__device__ __forceinline__ int h22bits(__half2 h) {
    union { int i; __half2 h; } u; u.h = h; return u.i;
}
__device__ __forceinline__ float h2f(unsigned short s) {
    union { unsigned short s; __half h; } u; u.s = s; return __half2float(u.h);
}

// ================= prep: fp32->fp16 cast (all blocks) + edge binning (first
// 1024 blocks). record: bits 0..17 = col, bits 18..26 = row % 512
__global__ __launch_bounds__(256) void prep_kernel(
        const float4* __restrict__ uw4, const float4* __restrict__ iw4,
        uint2* __restrict__ h,
        const int* __restrict__ row, const int* __restrict__ col,
        const float* __restrict__ val,
        int* __restrict__ bucket_cursor, int2* __restrict__ arena) {
    __shared__ int hist[NB];
    const int t = threadIdx.x;
    // ---- cast slice ----
    size_t i = (size_t)blockIdx.x * 256 + t;
    const size_t tot = (size_t)N_NODES * EMB / 4;
    if (i < tot) {
        const size_t nu = (size_t)NUM_USERS * EMB / 4;
        float4 v = (i < nu) ? uw4[i] : iw4[i - nu];
        h[i] = make_uint2(h22bits(__floats2half2_rn(v.x, v.y)),
                          h22bits(__floats2half2_rn(v.z, v.w)));
    }
    // ---- binning (blocks 0..BINA_BLK-1) ----
    if (blockIdx.x >= BINA_BLK) return;
    for (int k = t; k < NB; k += 256) hist[k] = 0;
    __syncthreads();
    const int per = (HALF_E + BINA_BLK - 1) / BINA_BLK;
    const int beg = blockIdx.x * per;
    const int end = min(beg + per, HALF_E);
    for (int e = beg + t; e < end; e += 256) {
        int r = row[e], c = col[e];
        atomicAdd(&hist[r >> 9], 1);
        atomicAdd(&hist[c >> 9], 1);
    }
    __syncthreads();
    for (int k = t; k < NB; k += 256) {
        int cnt = hist[k];
        int base = cnt ? atomicAdd(&bucket_cursor[k], cnt) : 0;
        hist[k] = k * CAP + base;     // global arena slot cursor for this block
    }
    __syncthreads();
    for (int e = beg + t; e < end; e += 256) {
        int r = row[e], c = col[e];
        float v1 = val[e], v2 = val[e + HALF_E];
        int s1 = atomicAdd(&hist[r >> 9], 1);   // LDS atomic -> local rank
        int s2 = atomicAdd(&hist[c >> 9], 1);
        arena[s1] = make_int2(c | ((r & 511) << 18), __float_as_int(v1));
        arena[s2] = make_int2(r | ((c & 511) << 18), __float_as_int(v2));
    }
}

// exclusive scan of NB bucket counts -> global CSR base per bucket
__global__ __launch_bounds__(256) void bucket_scan(
        const int* __restrict__ bucket_cursor, int* __restrict__ bucket_base,
        int* __restrict__ rowptr) {
    __shared__ int sm[256];
    const int t = threadIdx.x;
    const int K = (NB + 255) / 256;   // 2
    int v[K], s = 0;
    #pragma unroll
    for (int j = 0; j < K; j++) {
        int idx = t * K + j;
        v[j] = (idx < NB) ? bucket_cursor[idx] : 0;
        s += v[j];
    }
    sm[t] = s;
    __syncthreads();
    for (int m = 1; m < 256; m <<= 1) {
        int y = (t >= m) ? sm[t - m] : 0;
        __syncthreads();
        sm[t] += y;
        __syncthreads();
    }
    int excl = sm[t] - s;
    #pragma unroll
    for (int j = 0; j < K; j++) {
        int idx = t * K + j;
        if (idx < NB) bucket_base[idx] = excl;
        excl += v[j];
    }
    if (t == 0) rowptr[N_NODES] = N_EDGES;
}

// ================= per-bucket counting sort -> CSR + rowptr =======
// R13: 1024-thread blocks (4x intra-block parallelism; R12 occ was 14%).
// Two passes over the (L3-resident) arena; LDS ~3 KB. val fp32 -> half2
// packed here so spmm's inner loop has zero converts.
__global__ __launch_bounds__(1024) void bin_sort(
        const int* __restrict__ bucket_cursor, const int* __restrict__ bucket_base,
        const int2* __restrict__ arena,
        int* __restrict__ rowptr, int2* __restrict__ colval) {
    __shared__ int rcnt[BROWS];
    __shared__ int sm[256];
    const int bin = blockIdx.x;
    const int t = threadIdx.x;
    const int total = bucket_cursor[bin];
    const int count = min(total, CAP);
    const int gbase = bucket_base[bin];
    if (t < BROWS) rcnt[t] = 0;
    __syncthreads();
    for (int i = t; i < count; i += 1024) {
        int rx = arena[bin * CAP + i].x >> 18;
        atomicAdd(&rcnt[rx], 1);
    }
    __syncthreads();
    // exclusive scan of 512 counts: first 256 threads, 2 counts each
    int v0 = 0, v1 = 0, s = 0;
    if (t < 256) {
        v0 = rcnt[2 * t]; v1 = rcnt[2 * t + 1];
        s = v0 + v1;
        sm[t] = s;
    }
    __syncthreads();
    for (int m = 1; m < 256; m <<= 1) {
        int y = (t < 256 && t >= m) ? sm[t - m] : 0;
        __syncthreads();
        if (t < 256) sm[t] += y;
        __syncthreads();
    }
    if (t < 256) {
        int excl = sm[t] - s;
        rcnt[2 * t] = excl;
        rcnt[2 * t + 1] = excl + v0;
        int r0 = bin * BROWS + 2 * t;
        if (r0 < N_NODES) rowptr[r0] = gbase + excl;
        if (r0 + 1 < N_NODES) rowptr[r0 + 1] = gbase + excl + v0;
    }
    __syncthreads();
    for (int i = t; i < count; i += 1024) {
        int2 rec = arena[bin * CAP + i];
        int pos = atomicAdd(&rcnt[rec.x >> 18], 1);
        __half2 hv = __float2half2_rn(__int_as_float(rec.y));
        colval[gbase + pos] = make_int2(rec.x & 0x3FFFF, h22bits(hv));
    }
    // harden: zero-fill any overflow gap (dropped edges, never a fault)
    for (int i = count + t; i < total; i += 1024)
        colval[gbase + i] = make_int2(0, 0);
}

// ================= gather SpMM (fp16): h_next[r] = sum val*h_cur[col] ========
// wave = 8 edge-groups x 8 lanes x uint4 (16B/lane = 8 halves, 128B/row).
// 8 row-gathers per wave-inst + 2-deep pipeline -> ~24 gathers in flight.
__global__ __launch_bounds__(256) void spmm_csr(
        const int* __restrict__ rowptr, const int2* __restrict__ colval,
        const unsigned short* __restrict__ h_cur, unsigned short* __restrict__ h_next) {
    const int t = threadIdx.x;
    const int lane = t & 63;
    const int g = lane >> 3;          // edge sub-slot 0..7
    const int l = lane & 7;           // uint4 index within row
    int r = blockIdx.x * 4 + (t >> 6);
    if (r >= N_NODES) return;
    const int beg = rowptr[r], end = rowptr[r + 1];
    __half2 ac0 = __float2half2_rn(0.0f), ac1 = ac0, ac2 = ac0, ac3 = ac0;
    int e = beg + g;
    if (e < end) {
        int2 cv = colval[e];
        uint4 x = ((const uint4*)(h_cur + (size_t)cv.x * EMB))[l];
        e += 8;
        if (e < end) {
            int2 cv2 = colval[e];
            uint4 x2 = ((const uint4*)(h_cur + (size_t)cv2.x * EMB))[l];
            for (e += 8; e < end; e += 8) {
                int2 cv3 = colval[e];
                uint4 x3 = ((const uint4*)(h_cur + (size_t)cv3.x * EMB))[l];
                __half2 vv = bits2h2(cv.y);
                ac0 = __hfma2(vv, bits2h2(x.x), ac0);
                ac1 = __hfma2(vv, bits2h2(x.y), ac1);
                ac2 = __hfma2(vv, bits2h2(x.z), ac2);
                ac3 = __hfma2(vv, bits2h2(x.w), ac3);
                cv = cv2; x = x2; cv2 = cv3; x2 = x3;
            }
            __half2 vv = bits2h2(cv.y);
            ac0 = __hfma2(vv, bits2h2(x.x), ac0);
            ac1 = __hfma2(vv, bits2h2(x.y), ac1);
            ac2 = __hfma2(vv, bits2h2(x.z), ac2);
            ac3 = __hfma2(vv, bits2h2(x.w), ac3);
            cv = cv2; x = x2;
        }
        __half2 vv = bits2h2(cv.y);
        ac0 = __hfma2(vv, bits2h2(x.x), ac0);
        ac1 = __hfma2(vv, bits2h2(x.y), ac1);
        ac2 = __hfma2(vv, bits2h2(x.z), ac2);
        ac3 = __hfma2(vv, bits2h2(x.w), ac3);
    }
    // reduce across the 8 edge-groups (lane bits 3..5)
    int a0 = h22bits(ac0), a1 = h22bits(ac1), a2 = h22bits(ac2), a3 = h22bits(ac3);
    #pragma unroll
    for (int m = 8; m < 64; m <<= 1) {
        a0 = h22bits(__hadd2(bits2h2(a0), bits2h2(__shfl_xor(a0, m, 64))));
        a1 = h22bits(__hadd2(bits2h2(a1), bits2h2(__shfl_xor(a1, m, 64))));
        a2 = h22bits(__hadd2(bits2h2(a2), bits2h2(__shfl_xor(a2, m, 64))));
        a3 = h22bits(__hadd2(bits2h2(a3), bits2h2(__shfl_xor(a3, m, 64))));
    }
    if (g == 0)
        ((uint4*)(h_next + (size_t)r * EMB))[l] =
            make_uint4((unsigned)a0, (unsigned)a1, (unsigned)a2, (unsigned)a3);
}

// ---- layer-3 sparsification, fused with the e2 self-row add; STORES
// sel[b] = f32(h_cur[r]) + sum_e val*h_cur[col]  (e0/e1 live in batch_loss)
__global__ __launch_bounds__(256) void spmm_sel(
        const int* __restrict__ rowptr, const int2* __restrict__ colval,
        const int* __restrict__ user, const int* __restrict__ pos,
        const int* __restrict__ neg,
        const unsigned short* __restrict__ h_cur, float* __restrict__ sel) {
    const int t = threadIdx.x;
    const int lane = t & 63;
    const int g = lane >> 3;
    const int l = lane & 7;
    int b = blockIdx.x * 4 + (t >> 6);
    if (b >= 3 * BATCH) return;
    int which = b / BATCH, bb = b - which * BATCH;
    int r = (which == 0) ? user[bb]
          : NUM_USERS + ((which == 1) ? pos[bb] : neg[bb]);
    const int beg = rowptr[r], end = rowptr[r + 1];
    __half2 ac0 = __float2half2_rn(0.0f), ac1 = ac0, ac2 = ac0, ac3 = ac0;
    int e = beg + g;
    if (e < end) {
        int2 cv = colval[e];
        uint4 x = ((const uint4*)(h_cur + (size_t)cv.x * EMB))[l];
        e += 8;
        if (e < end) {
            int2 cv2 = colval[e];
            uint4 x2 = ((const uint4*)(h_cur + (size_t)cv2.x * EMB))[l];
            for (e += 8; e < end; e += 8) {
                int2 cv3 = colval[e];
                uint4 x3 = ((const uint4*)(h_cur + (size_t)cv3.x * EMB))[l];
                __half2 vv = bits2h2(cv.y);
                ac0 = __hfma2(vv, bits2h2(x.x), ac0);
                ac1 = __hfma2(vv, bits2h2(x.y), ac1);
                ac2 = __hfma2(vv, bits2h2(x.z), ac2);
                ac3 = __hfma2(vv, bits2h2(x.w), ac3);
                cv = cv2; x = x2; cv2 = cv3; x2 = x3;
            }
            __half2 vv = bits2h2(cv.y);
            ac0 = __hfma2(vv, bits2h2(x.x), ac0);
            ac1 = __hfma2(vv, bits2h2(x.y), ac1);
            ac2 = __hfma2(vv, bits2h2(x.z), ac2);
            ac3 = __hfma2(vv, bits2h2(x.w), ac3);
            cv = cv2; x = x2;
        }
        __half2 vv = bits2h2(cv.y);
        ac0 = __hfma2(vv, bits2h2(x.x), ac0);
        ac1 = __hfma2(vv, bits2h2(x.y), ac1);
        ac2 = __hfma2(vv, bits2h2(x.z), ac2);
        ac3 = __hfma2(vv, bits2h2(x.w), ac3);
    }
    int a0 = h22bits(ac0), a1 = h22bits(ac1), a2 = h22bits(ac2), a3 = h22bits(ac3);
    #pragma unroll
    for (int m = 8; m < 64; m <<= 1) {
        a0 = h22bits(__hadd2(bits2h2(a0), bits2h2(__shfl_xor(a0, m, 64))));
        a1 = h22bits(__hadd2(bits2h2(a1), bits2h2(__shfl_xor(a1, m, 64))));
        a2 = h22bits(__hadd2(bits2h2(a2), bits2h2(__shfl_xor(a2, m, 64))));
        a3 = h22bits(__hadd2(bits2h2(a3), bits2h2(__shfl_xor(a3, m, 64))));
    }
    if (g == 0) {
        float2 f0 = __half22float2(bits2h2(a0));
        float2 f1 = __half22float2(bits2h2(a1));
        float2 f2 = __half22float2(bits2h2(a2));
        float2 f3 = __half22float2(bits2h2(a3));
        uint4 hx = ((const uint4*)(h_cur + (size_t)r * EMB))[l];  // e2 self-row
        float2 s0 = __half22float2(bits2h2((int)hx.x));
        float2 s1 = __half22float2(bits2h2((int)hx.y));
        float2 s2 = __half22float2(bits2h2((int)hx.z));
        float2 s3 = __half22float2(bits2h2((int)hx.w));
        float4* dst = (float4*)(sel + (size_t)b * EMB);
        dst[2 * l]     = make_float4(f0.x + s0.x, f0.y + s0.y, f1.x + s1.x, f1.y + s1.y);
        dst[2 * l + 1] = make_float4(f2.x + s2.x, f2.y + s2.y, f3.x + s3.x, f3.y + s3.y);
    }
}

// ---------- per-batch losses + normalized vectors ----------
// fuses the e0 (fp32 weights) and e1 (h1 table) gathers; sel holds e2+e3.
__global__ __launch_bounds__(256) void batch_loss(
        const int* __restrict__ user, const int* __restrict__ pos,
        const int* __restrict__ neg,
        const float* __restrict__ uw, const float* __restrict__ iw,
        const unsigned short* __restrict__ h1,
        const float* __restrict__ sel,
        float* __restrict__ un, float* __restrict__ pn,
        float* __restrict__ diag,
        float* __restrict__ pbpr, float* __restrict__ preg) {
    __shared__ float lb[4], lr[4];
    const int t = threadIdx.x;
    const int lane = t & 63;
    const int w = t >> 6;
    int b = blockIdx.x * 4 + w;
    const float inv4 = 0.25f;  // / (GCN_LAYERS + 1)
    int nu = user[b], np = pos[b], ng = neg[b];
    float u = (uw[(size_t)nu * EMB + lane]
             + h2f(h1[(size_t)nu * EMB + lane])
             + sel[(size_t)b * EMB + lane]) * inv4;
    float p = (iw[(size_t)np * EMB + lane]
             + h2f(h1[(size_t)(NUM_USERS + np) * EMB + lane])
             + sel[(size_t)(BATCH + b) * EMB + lane]) * inv4;
    float n = (iw[(size_t)ng * EMB + lane]
             + h2f(h1[(size_t)(NUM_USERS + ng) * EMB + lane])
             + sel[(size_t)(2 * BATCH + b) * EMB + lane]) * inv4;
    float pos_s = wave_sum(u * p);
    float neg_s = wave_sum(u * n);
    float uu = wave_sum(u * u);
    float pp = wave_sum(p * p);
    float nn = wave_sum(n * n);
    float ru = rsqrtf(uu), rp = rsqrtf(pp);
    un[(size_t)b * EMB + lane] = u * ru;
    pn[(size_t)b * EMB + lane] = p * rp;
    if (lane == 0) {
        diag[b] = pos_s * ru * rp * (1.0f / TAU);
        float d = pos_s - neg_s;
        float tt = -d;
        lb[w] = fmaxf(tt, 0.0f) + log1pf(expf(-fabsf(tt)));  // softplus(-d)
        lr[w] = uu + pp + nn;
    }
    __syncthreads();
    if (t == 0) {
        pbpr[blockIdx.x] = lb[0] + lb[1] + lb[2] + lb[3];
        preg[blockIdx.x] = lr[0] + lr[1] + lr[2] + lr[3];
    }
}

// ================= SSL as register-tiled GEMM =================
// per-j-tile partials rowsum_p[jt][i] (written once) -> no atomics/memset.
#define TS 128
__global__ __launch_bounds__(256) void ssl_gemm(
        const float* __restrict__ un, const float* __restrict__ pn,
        float* __restrict__ rowsum_p) {
    __shared__ float ua[EMB][TS];  // [k][i]
    __shared__ float pb[EMB][TS];  // [k][j]
    const int t = threadIdx.x;
    const int it = blockIdx.x & 31, jt = blockIdx.x >> 5;
    const int i0 = it * TS;
    const int j0 = jt * TS;
    for (int x = t; x < TS * 16; x += 256) {
        int i = x & (TS - 1), d4 = x >> 7;
        float4 v = ((const float4*)(un + (size_t)(i0 + i) * EMB))[d4];
        ua[d4 * 4 + 0][i] = v.x; ua[d4 * 4 + 1][i] = v.y;
        ua[d4 * 4 + 2][i] = v.z; ua[d4 * 4 + 3][i] = v.w;
        float4 w = ((const float4*)(pn + (size_t)(j0 + i) * EMB))[d4];
        pb[d4 * 4 + 0][i] = w.x; pb[d4 * 4 + 1][i] = w.y;
        pb[d4 * 4 + 2][i] = w.z; pb[d4 * 4 + 3][i] = w.w;
    }
    __syncthreads();
    const int tx = t & 15, ty = t >> 4;
    float c[8][8];
    #pragma unroll
    for (int p = 0; p < 8; p++)
        #pragma unroll
        for (int q = 0; q < 8; q++) c[p][q] = 0.0f;
    for (int k = 0; k < EMB; k++) {
        float a[8], b[8];
        #pragma unroll
        for (int q = 0; q < 8; q++) { a[q] = ua[k][ty * 8 + q]; b[q] = pb[k][tx * 8 + q]; }
        #pragma unroll
        for (int p = 0; p < 8; p++)
            #pragma unroll
            for (int q = 0; q < 8; q++) c[p][q] = fmaf(a[p], b[q], c[p][q]);
    }
    float s[8];
    #pragma unroll
    for (int p = 0; p < 8; p++) {
        s[p] = 0.0f;
        #pragma unroll
        for (int q = 0; q < 8; q++) s[p] += __expf(c[p][q] * (1.0f / TAU));
    }
    #pragma unroll
    for (int m = 1; m < 16; m <<= 1)
        #pragma unroll
        for (int p = 0; p < 8; p++) s[p] += __shfl_xor(s[p], m, 64);
    if (tx == 0) {
        #pragma unroll
        for (int p = 0; p < 8; p++)
            rowsum_p[(size_t)jt * BATCH + i0 + ty * 8 + p] = s[p];
    }
}

// single block: reduce rowsum partials + ssl terms + bpr/reg partials -> loss
__global__ __launch_bounds__(256) void finalize(
        const float* __restrict__ rowsum_p, const float* __restrict__ diag,
        const float* __restrict__ pbpr, const float* __restrict__ preg,
        float* __restrict__ out) {
    __shared__ float red[3][4];
    const int t = threadIdx.x;
    float sb = 0.0f, sr = 0.0f, ss = 0.0f;
    for (int i = t; i < BATCH / 4; i += 256) { sb += pbpr[i]; sr += preg[i]; }
    for (int i = t; i < BATCH; i += 256) {
        float rs = 0.0f;
        #pragma unroll
        for (int j = 0; j < 32; j++) rs += rowsum_p[(size_t)j * BATCH + i];
        ss += logf(rs) - diag[i];
    }
    sb = wave_sum(sb); sr = wave_sum(sr); ss = wave_sum(ss);
    const int w = t >> 6;
    if ((t & 63) == 0) { red[0][w] = sb; red[1][w] = sr; red[2][w] = ss; }
    __syncthreads();
    if (t == 0) {
        float bpr_sum = red[0][0] + red[0][1] + red[0][2] + red[0][3];
        float reg_sum = red[1][0] + red[1][1] + red[1][2] + red[1][3];
        float ssl_sum = red[2][0] + red[2][1] + red[2][2] + red[2][3];
        float bpr = bpr_sum * (1.0f / BATCH);
        float reg = 0.5f * reg_sum * (1.0f / BATCH) * REG_LAMBDA;
        float ssl = ssl_sum * (1.0f / BATCH) * SSL_LAMBDA;
        out[0] = bpr + reg + ssl;
    }
}

extern "C" void kernel_launch(void* const* d_in, const int* in_sizes, int n_in,
                              void* d_out, int out_size, void* d_ws, size_t ws_size,
                              hipStream_t stream) {
    const int*   user    = (const int*)d_in[0];
    const int*   pos     = (const int*)d_in[1];
    const int*   neg     = (const int*)d_in[2];
    const int*   adj_row = (const int*)d_in[3];
    const int*   adj_col = (const int*)d_in[4];
    const float* adj_val = (const float*)d_in[5];
    const float* user_w  = (const float*)d_in[6];
    const float* item_w  = (const float*)d_in[7];
    float* out = (float*)d_out;

    // ---- workspace layout ----
    unsigned short* hA = (unsigned short*)d_ws;            // fp16 table (19.2 MB)
    unsigned short* hB = hA + (size_t)N_NODES * EMB;       // fp16 table (19.2 MB)
    float* buf1   = (float*)d_ws + (size_t)N_NODES * EMB;  // 38.4 MB arena region
    float* sel    = buf1 + (size_t)N_NODES * EMB;          // 786432 f
    float* un     = sel  + (size_t)3 * BATCH * EMB;        // 262144 f
    float* pn     = un   + (size_t)BATCH * EMB;            // 262144 f
    float* diag   = pn   + (size_t)BATCH * EMB;            // 4096 f
    float* rowsum_p = diag + BATCH;                        // 32*4096 f (512 KB)
    float* pbpr   = rowsum_p + 32 * BATCH;                 // 1024 f
    float* preg   = pbpr + 1024;                           // 1024 f
    int*   rowptr = (int*)(preg + 1024);                   // 150016 i
    int*   bucket_cursor = rowptr + 150016;                // 512 i  (memset)
    int*   bucket_base   = bucket_cursor + 512;            // 512 i
    int2*  colval = (int2*)(bucket_base + 512);            // 2.4M int2 (19.2 MB)
    int2*  arena  = (int2*)buf1;  // NB*CAP int2 = 31.95 MB <= 38.4 MB region

    hipMemsetAsync(bucket_cursor, 0, 512 * sizeof(int), stream);

    dim3 blk(256);

    // cast fp32->fp16 (all blocks) + edge binning (first 1024 blocks)
    prep_kernel<<<CAST_BLK, blk, 0, stream>>>((const float4*)user_w,
                                              (const float4*)item_w, (uint2*)hA,
                                              adj_row, adj_col, adj_val,
                                              bucket_cursor, arena);
    bucket_scan<<<1, blk, 0, stream>>>(bucket_cursor, bucket_base, rowptr);
    bin_sort<<<NB, dim3(1024), 0, stream>>>(bucket_cursor, bucket_base, arena,
                                            rowptr, colval);

    // layers 1,2: full spmm (fp16 tables); layer 3 + e2-add: spmm_sel (stores)
    spmm_csr<<<(N_NODES + 3) / 4, blk, 0, stream>>>(rowptr, colval, hA, hB);
    spmm_csr<<<(N_NODES + 3) / 4, blk, 0, stream>>>(rowptr, colval, hB, hA);
    spmm_sel<<<(3 * BATCH + 3) / 4, blk, 0, stream>>>(rowptr, colval, user, pos,
                                                      neg, hA, sel);

    // batch_loss fuses e0 (fp32 weights) + e1 (hB) gathers with the loss math
    batch_loss<<<BATCH / 4, blk, 0, stream>>>(user, pos, neg, user_w, item_w,
                                              hB, sel, un, pn, diag, pbpr, preg);
    ssl_gemm<<<(BATCH / TS) * (BATCH / TS), blk, 0, stream>>>(un, pn, rowsum_p);
    finalize<<<1, blk, 0, stream>>>(rowsum_p, diag, pbpr, preg, out);
}

// Round 14
// 317.543 us; speedup vs baseline: 1.0991x; 1.0991x over previous
//
#include <hip/hip_runtime.h>
#include <hip/hip_fp16.h>
#include <math.h>

#define NUM_USERS 100000
#define NUM_ITEMS 50000
#define N_NODES   150000   // NUM_USERS + NUM_ITEMS
#define N_EDGES   2400000
#define HALF_E    (N_EDGES / 2)
#define EMB       64
#define BATCH     4096
#define TAU        0.2f
#define SSL_LAMBDA 0.1f
#define REG_LAMBDA 1e-4f

// ---- binned CSR build (coarse 512-row buckets) ----
// R14: R13 regression root-caused to open-sector write amp: B*NB partially
// filled 64B sectors (9.6-19 MB) >> 4MB/XCD L2 -> evict/RMW. Fix: block-local
// counting sort in LDS, then LINEAR write-out (mean 128B full runs).
#define NB        293           // 293*512 = 150016 >= N_NODES
#define BROWS     512
#define CAP       13632         // item-bucket mean 12288 + 12 sigma
#define BINA_BLK  512
#define PER_BLK   ((HALF_E + BINA_BLK - 1) / BINA_BLK)   // 2344 edge-pairs
#define EBUF_CAP  (2 * PER_BLK)                          // 4688 records (37.5 KB)
#define CAST_BLK  9375          // 150000*64/4 threads / 256

// ---------- helpers ----------
__device__ __forceinline__ float wave_sum(float v) {
    #pragma unroll
    for (int m = 1; m < 64; m <<= 1) v += __shfl_xor(v, m, 64);
    return v;
}
__device__ __forceinline__ __half2 bits2h2(int b) {
    union { int i; __half2 h; } u; u.i = b; return u.h;
}
__device__ __forceinline__ int h22bits(__half2 h) {
    union { int i; __half2 h; } u; u.h = h; return u.i;
}
__device__ __forceinline__ float h2f(unsigned short s) {
    union { unsigned short s; __half h; } u; u.s = s; return __half2float(u.h);
}
__device__ __forceinline__ unsigned short f2h_bits(float x) {
    union { __half h; unsigned short s; } u; u.h = __float2half_rn(x); return u.s;
}

// ================= prep: fp32->fp16 cast (all blocks) + edge binning with
// block-local counting sort (first 512 blocks).
// arena record: x = col | (row%512)<<18 ; y = (bucket<<16) | half(val)
__global__ __launch_bounds__(256) void prep_kernel(
        const float4* __restrict__ uw4, const float4* __restrict__ iw4,
        uint2* __restrict__ h,
        const int* __restrict__ row, const int* __restrict__ col,
        const float* __restrict__ val,
        int* __restrict__ bucket_cursor, int2* __restrict__ arena) {
    __shared__ int hist[NB];      // counts -> local running cursor
    __shared__ int lbase[NB];     // local exclusive base
    __shared__ int delta[NB];     // arena_run_start - lbase
    __shared__ int sm[256];
    __shared__ int2 ebuf[EBUF_CAP];
    const int t = threadIdx.x;
    // ---- cast slice ----
    size_t i = (size_t)blockIdx.x * 256 + t;
    const size_t tot = (size_t)N_NODES * EMB / 4;
    if (i < tot) {
        const size_t nu = (size_t)NUM_USERS * EMB / 4;
        float4 v = (i < nu) ? uw4[i] : iw4[i - nu];
        h[i] = make_uint2(h22bits(__floats2half2_rn(v.x, v.y)),
                          h22bits(__floats2half2_rn(v.z, v.w)));
    }
    // ---- binning (blocks 0..BINA_BLK-1) ----
    if (blockIdx.x >= BINA_BLK) return;
    for (int k = t; k < NB; k += 256) hist[k] = 0;
    __syncthreads();
    const int beg = blockIdx.x * PER_BLK;
    const int end = min(beg + PER_BLK, HALF_E);
    for (int e = beg + t; e < end; e += 256) {
        int r = row[e], c = col[e];
        atomicAdd(&hist[r >> 9], 1);
        atomicAdd(&hist[c >> 9], 1);
    }
    __syncthreads();
    // local exclusive scan of NB counts (2 per thread)
    int v0 = (2 * t < NB) ? hist[2 * t] : 0;
    int v1 = (2 * t + 1 < NB) ? hist[2 * t + 1] : 0;
    int s = v0 + v1;
    sm[t] = s;
    __syncthreads();
    for (int m = 1; m < 256; m <<= 1) {
        int y = (t >= m) ? sm[t - m] : 0;
        __syncthreads();
        sm[t] += y;
        __syncthreads();
    }
    int excl = sm[t] - s;
    if (2 * t < NB) lbase[2 * t] = excl;
    if (2 * t + 1 < NB) lbase[2 * t + 1] = excl + v0;
    __syncthreads();
    // reserve global runs; delta maps local index -> arena slot
    for (int k = t; k < NB; k += 256) {
        int cnt = hist[k];
        int gb = cnt ? atomicAdd(&bucket_cursor[k], cnt) : 0;
        delta[k] = (k * CAP + gb) - lbase[k];
    }
    __syncthreads();
    for (int k = t; k < NB; k += 256) hist[k] = lbase[k];  // running cursor
    __syncthreads();
    // pass 2: scatter records into LDS sorted-by-bucket buffer
    for (int e = beg + t; e < end; e += 256) {
        int r = row[e], c = col[e];
        unsigned short h1 = f2h_bits(val[e]);
        unsigned short h2v = f2h_bits(val[e + HALF_E]);
        int b1 = r >> 9, b2 = c >> 9;
        int p1 = atomicAdd(&hist[b1], 1);
        int p2 = atomicAdd(&hist[b2], 1);
        ebuf[p1] = make_int2(c | ((r & 511) << 18), (b1 << 16) | h1);
        ebuf[p2] = make_int2(r | ((c & 511) << 18), (b2 << 16) | h2v);
    }
    __syncthreads();
    // linear write-out: consecutive i in a bucket -> consecutive arena slots
    const int count = 2 * (end - beg);
    for (int k = t; k < count; k += 256) {
        int2 rec = ebuf[k];
        int b = rec.y >> 16;        // bucket (9 bits, positive)
        arena[k + delta[b]] = rec;
    }
}

// exclusive scan of NB bucket counts -> global CSR base per bucket
__global__ __launch_bounds__(256) void bucket_scan(
        const int* __restrict__ bucket_cursor, int* __restrict__ bucket_base,
        int* __restrict__ rowptr) {
    __shared__ int sm[256];
    const int t = threadIdx.x;
    const int K = (NB + 255) / 256;   // 2
    int v[K], s = 0;
    #pragma unroll
    for (int j = 0; j < K; j++) {
        int idx = t * K + j;
        v[j] = (idx < NB) ? bucket_cursor[idx] : 0;
        s += v[j];
    }
    sm[t] = s;
    __syncthreads();
    for (int m = 1; m < 256; m <<= 1) {
        int y = (t >= m) ? sm[t - m] : 0;
        __syncthreads();
        sm[t] += y;
        __syncthreads();
    }
    int excl = sm[t] - s;
    #pragma unroll
    for (int j = 0; j < K; j++) {
        int idx = t * K + j;
        if (idx < NB) bucket_base[idx] = excl;
        excl += v[j];
    }
    if (t == 0) rowptr[N_NODES] = N_EDGES;
}

// ================= per-bucket counting sort -> CSR + rowptr =======
// 1024-thread blocks; two passes over the (L3-resident) arena; LDS ~3 KB.
// arena.y low 16 bits = half(val) -> broadcast to half2 for colval.
__global__ __launch_bounds__(1024) void bin_sort(
        const int* __restrict__ bucket_cursor, const int* __restrict__ bucket_base,
        const int2* __restrict__ arena,
        int* __restrict__ rowptr, int2* __restrict__ colval) {
    __shared__ int rcnt[BROWS];
    __shared__ int sm[256];
    const int bin = blockIdx.x;
    const int t = threadIdx.x;
    const int total = bucket_cursor[bin];
    const int count = min(total, CAP);
    const int gbase = bucket_base[bin];
    if (t < BROWS) rcnt[t] = 0;
    __syncthreads();
    for (int i = t; i < count; i += 1024) {
        int rx = arena[bin * CAP + i].x >> 18;
        atomicAdd(&rcnt[rx & 511], 1);
    }
    __syncthreads();
    // exclusive scan of 512 counts: first 256 threads, 2 counts each
    int v0 = 0, v1 = 0, s = 0;
    if (t < 256) {
        v0 = rcnt[2 * t]; v1 = rcnt[2 * t + 1];
        s = v0 + v1;
        sm[t] = s;
    }
    __syncthreads();
    for (int m = 1; m < 256; m <<= 1) {
        int y = (t < 256 && t >= m) ? sm[t - m] : 0;
        __syncthreads();
        if (t < 256) sm[t] += y;
        __syncthreads();
    }
    if (t < 256) {
        int excl = sm[t] - s;
        rcnt[2 * t] = excl;
        rcnt[2 * t + 1] = excl + v0;
        int r0 = bin * BROWS + 2 * t;
        if (r0 < N_NODES) rowptr[r0] = gbase + excl;
        if (r0 + 1 < N_NODES) rowptr[r0 + 1] = gbase + excl + v0;
    }
    __syncthreads();
    for (int i = t; i < count; i += 1024) {
        int2 rec = arena[bin * CAP + i];
        int pos = atomicAdd(&rcnt[(rec.x >> 18) & 511], 1);
        unsigned int hv = (unsigned int)rec.y & 0xFFFFu;
        colval[gbase + pos] = make_int2(rec.x & 0x3FFFF, (int)(hv * 0x10001u));
    }
    // harden: zero-fill any overflow gap (dropped edges, never a fault)
    for (int i = count + t; i < total; i += 1024)
        colval[gbase + i] = make_int2(0, 0);
}

// ================= gather SpMM (fp16): h_next[r] = sum val*h_cur[col] ========
// wave = 8 edge-groups x 8 lanes x uint4 (16B/lane = 8 halves, 128B/row).
// 8 row-gathers per wave-inst + 2-deep pipeline -> ~24 gathers in flight.
__global__ __launch_bounds__(256) void spmm_csr(
        const int* __restrict__ rowptr, const int2* __restrict__ colval,
        const unsigned short* __restrict__ h_cur, unsigned short* __restrict__ h_next) {
    const int t = threadIdx.x;
    const int lane = t & 63;
    const int g = lane >> 3;          // edge sub-slot 0..7
    const int l = lane & 7;           // uint4 index within row
    int r = blockIdx.x * 4 + (t >> 6);
    if (r >= N_NODES) return;
    const int beg = rowptr[r], end = rowptr[r + 1];
    __half2 ac0 = __float2half2_rn(0.0f), ac1 = ac0, ac2 = ac0, ac3 = ac0;
    int e = beg + g;
    if (e < end) {
        int2 cv = colval[e];
        uint4 x = ((const uint4*)(h_cur + (size_t)cv.x * EMB))[l];
        e += 8;
        if (e < end) {
            int2 cv2 = colval[e];
            uint4 x2 = ((const uint4*)(h_cur + (size_t)cv2.x * EMB))[l];
            for (e += 8; e < end; e += 8) {
                int2 cv3 = colval[e];
                uint4 x3 = ((const uint4*)(h_cur + (size_t)cv3.x * EMB))[l];
                __half2 vv = bits2h2(cv.y);
                ac0 = __hfma2(vv, bits2h2(x.x), ac0);
                ac1 = __hfma2(vv, bits2h2(x.y), ac1);
                ac2 = __hfma2(vv, bits2h2(x.z), ac2);
                ac3 = __hfma2(vv, bits2h2(x.w), ac3);
                cv = cv2; x = x2; cv2 = cv3; x2 = x3;
            }
            __half2 vv = bits2h2(cv.y);
            ac0 = __hfma2(vv, bits2h2(x.x), ac0);
            ac1 = __hfma2(vv, bits2h2(x.y), ac1);
            ac2 = __hfma2(vv, bits2h2(x.z), ac2);
            ac3 = __hfma2(vv, bits2h2(x.w), ac3);
            cv = cv2; x = x2;
        }
        __half2 vv = bits2h2(cv.y);
        ac0 = __hfma2(vv, bits2h2(x.x), ac0);
        ac1 = __hfma2(vv, bits2h2(x.y), ac1);
        ac2 = __hfma2(vv, bits2h2(x.z), ac2);
        ac3 = __hfma2(vv, bits2h2(x.w), ac3);
    }
    // reduce across the 8 edge-groups (lane bits 3..5)
    int a0 = h22bits(ac0), a1 = h22bits(ac1), a2 = h22bits(ac2), a3 = h22bits(ac3);
    #pragma unroll
    for (int m = 8; m < 64; m <<= 1) {
        a0 = h22bits(__hadd2(bits2h2(a0), bits2h2(__shfl_xor(a0, m, 64))));
        a1 = h22bits(__hadd2(bits2h2(a1), bits2h2(__shfl_xor(a1, m, 64))));
        a2 = h22bits(__hadd2(bits2h2(a2), bits2h2(__shfl_xor(a2, m, 64))));
        a3 = h22bits(__hadd2(bits2h2(a3), bits2h2(__shfl_xor(a3, m, 64))));
    }
    if (g == 0)
        ((uint4*)(h_next + (size_t)r * EMB))[l] =
            make_uint4((unsigned)a0, (unsigned)a1, (unsigned)a2, (unsigned)a3);
}

// ---- layer-3 sparsification, fused with the e2 self-row add; STORES
// sel[b] = f32(h_cur[r]) + sum_e val*h_cur[col]  (e0/e1 live in batch_loss)
__global__ __launch_bounds__(256) void spmm_sel(
        const int* __restrict__ rowptr, const int2* __restrict__ colval,
        const int* __restrict__ user, const int* __restrict__ pos,
        const int* __restrict__ neg,
        const unsigned short* __restrict__ h_cur, float* __restrict__ sel) {
    const int t = threadIdx.x;
    const int lane = t & 63;
    const int g = lane >> 3;
    const int l = lane & 7;
    int b = blockIdx.x * 4 + (t >> 6);
    if (b >= 3 * BATCH) return;
    int which = b / BATCH, bb = b - which * BATCH;
    int r = (which == 0) ? user[bb]
          : NUM_USERS + ((which == 1) ? pos[bb] : neg[bb]);
    const int beg = rowptr[r], end = rowptr[r + 1];
    __half2 ac0 = __float2half2_rn(0.0f), ac1 = ac0, ac2 = ac0, ac3 = ac0;
    int e = beg + g;
    if (e < end) {
        int2 cv = colval[e];
        uint4 x = ((const uint4*)(h_cur + (size_t)cv.x * EMB))[l];
        e += 8;
        if (e < end) {
            int2 cv2 = colval[e];
            uint4 x2 = ((const uint4*)(h_cur + (size_t)cv2.x * EMB))[l];
            for (e += 8; e < end; e += 8) {
                int2 cv3 = colval[e];
                uint4 x3 = ((const uint4*)(h_cur + (size_t)cv3.x * EMB))[l];
                __half2 vv = bits2h2(cv.y);
                ac0 = __hfma2(vv, bits2h2(x.x), ac0);
                ac1 = __hfma2(vv, bits2h2(x.y), ac1);
                ac2 = __hfma2(vv, bits2h2(x.z), ac2);
                ac3 = __hfma2(vv, bits2h2(x.w), ac3);
                cv = cv2; x = x2; cv2 = cv3; x2 = x3;
            }
            __half2 vv = bits2h2(cv.y);
            ac0 = __hfma2(vv, bits2h2(x.x), ac0);
            ac1 = __hfma2(vv, bits2h2(x.y), ac1);
            ac2 = __hfma2(vv, bits2h2(x.z), ac2);
            ac3 = __hfma2(vv, bits2h2(x.w), ac3);
            cv = cv2; x = x2;
        }
        __half2 vv = bits2h2(cv.y);
        ac0 = __hfma2(vv, bits2h2(x.x), ac0);
        ac1 = __hfma2(vv, bits2h2(x.y), ac1);
        ac2 = __hfma2(vv, bits2h2(x.z), ac2);
        ac3 = __hfma2(vv, bits2h2(x.w), ac3);
    }
    int a0 = h22bits(ac0), a1 = h22bits(ac1), a2 = h22bits(ac2), a3 = h22bits(ac3);
    #pragma unroll
    for (int m = 8; m < 64; m <<= 1) {
        a0 = h22bits(__hadd2(bits2h2(a0), bits2h2(__shfl_xor(a0, m, 64))));
        a1 = h22bits(__hadd2(bits2h2(a1), bits2h2(__shfl_xor(a1, m, 64))));
        a2 = h22bits(__hadd2(bits2h2(a2), bits2h2(__shfl_xor(a2, m, 64))));
        a3 = h22bits(__hadd2(bits2h2(a3), bits2h2(__shfl_xor(a3, m, 64))));
    }
    if (g == 0) {
        float2 f0 = __half22float2(bits2h2(a0));
        float2 f1 = __half22float2(bits2h2(a1));
        float2 f2 = __half22float2(bits2h2(a2));
        float2 f3 = __half22float2(bits2h2(a3));
        uint4 hx = ((const uint4*)(h_cur + (size_t)r * EMB))[l];  // e2 self-row
        float2 s0 = __half22float2(bits2h2((int)hx.x));
        float2 s1 = __half22float2(bits2h2((int)hx.y));
        float2 s2 = __half22float2(bits2h2((int)hx.z));
        float2 s3 = __half22float2(bits2h2((int)hx.w));
        float4* dst = (float4*)(sel + (size_t)b * EMB);
        dst[2 * l]     = make_float4(f0.x + s0.x, f0.y + s0.y, f1.x + s1.x, f1.y + s1.y);
        dst[2 * l + 1] = make_float4(f2.x + s2.x, f2.y + s2.y, f3.x + s3.x, f3.y + s3.y);
    }
}

// ---------- per-batch losses + normalized vectors ----------
// fuses the e0 (fp32 weights) and e1 (h1 table) gathers; sel holds e2+e3.
__global__ __launch_bounds__(256) void batch_loss(
        const int* __restrict__ user, const int* __restrict__ pos,
        const int* __restrict__ neg,
        const float* __restrict__ uw, const float* __restrict__ iw,
        const unsigned short* __restrict__ h1,
        const float* __restrict__ sel,
        float* __restrict__ un, float* __restrict__ pn,
        float* __restrict__ diag,
        float* __restrict__ pbpr, float* __restrict__ preg) {
    __shared__ float lb[4], lr[4];
    const int t = threadIdx.x;
    const int lane = t & 63;
    const int w = t >> 6;
    int b = blockIdx.x * 4 + w;
    const float inv4 = 0.25f;  // / (GCN_LAYERS + 1)
    int nu = user[b], np = pos[b], ng = neg[b];
    float u = (uw[(size_t)nu * EMB + lane]
             + h2f(h1[(size_t)nu * EMB + lane])
             + sel[(size_t)b * EMB + lane]) * inv4;
    float p = (iw[(size_t)np * EMB + lane]
             + h2f(h1[(size_t)(NUM_USERS + np) * EMB + lane])
             + sel[(size_t)(BATCH + b) * EMB + lane]) * inv4;
    float n = (iw[(size_t)ng * EMB + lane]
             + h2f(h1[(size_t)(NUM_USERS + ng) * EMB + lane])
             + sel[(size_t)(2 * BATCH + b) * EMB + lane]) * inv4;
    float pos_s = wave_sum(u * p);
    float neg_s = wave_sum(u * n);
    float uu = wave_sum(u * u);
    float pp = wave_sum(p * p);
    float nn = wave_sum(n * n);
    float ru = rsqrtf(uu), rp = rsqrtf(pp);
    un[(size_t)b * EMB + lane] = u * ru;
    pn[(size_t)b * EMB + lane] = p * rp;
    if (lane == 0) {
        diag[b] = pos_s * ru * rp * (1.0f / TAU);
        float d = pos_s - neg_s;
        float tt = -d;
        lb[w] = fmaxf(tt, 0.0f) + log1pf(expf(-fabsf(tt)));  // softplus(-d)
        lr[w] = uu + pp + nn;
    }
    __syncthreads();
    if (t == 0) {
        pbpr[blockIdx.x] = lb[0] + lb[1] + lb[2] + lb[3];
        preg[blockIdx.x] = lr[0] + lr[1] + lr[2] + lr[3];
    }
}

// ================= SSL as register-tiled GEMM =================
// per-j-tile partials rowsum_p[jt][i] (written once) -> no atomics/memset.
#define TS 128
__global__ __launch_bounds__(256) void ssl_gemm(
        const float* __restrict__ un, const float* __restrict__ pn,
        float* __restrict__ rowsum_p) {
    __shared__ float ua[EMB][TS];  // [k][i]
    __shared__ float pb[EMB][TS];  // [k][j]
    const int t = threadIdx.x;
    const int it = blockIdx.x & 31, jt = blockIdx.x >> 5;
    const int i0 = it * TS;
    const int j0 = jt * TS;
    for (int x = t; x < TS * 16; x += 256) {
        int i = x & (TS - 1), d4 = x >> 7;
        float4 v = ((const float4*)(un + (size_t)(i0 + i) * EMB))[d4];
        ua[d4 * 4 + 0][i] = v.x; ua[d4 * 4 + 1][i] = v.y;
        ua[d4 * 4 + 2][i] = v.z; ua[d4 * 4 + 3][i] = v.w;
        float4 w = ((const float4*)(pn + (size_t)(j0 + i) * EMB))[d4];
        pb[d4 * 4 + 0][i] = w.x; pb[d4 * 4 + 1][i] = w.y;
        pb[d4 * 4 + 2][i] = w.z; pb[d4 * 4 + 3][i] = w.w;
    }
    __syncthreads();
    const int tx = t & 15, ty = t >> 4;
    float c[8][8];
    #pragma unroll
    for (int p = 0; p < 8; p++)
        #pragma unroll
        for (int q = 0; q < 8; q++) c[p][q] = 0.0f;
    for (int k = 0; k < EMB; k++) {
        float a[8], b[8];
        #pragma unroll
        for (int q = 0; q < 8; q++) { a[q] = ua[k][ty * 8 + q]; b[q] = pb[k][tx * 8 + q]; }
        #pragma unroll
        for (int p = 0; p < 8; p++)
            #pragma unroll
            for (int q = 0; q < 8; q++) c[p][q] = fmaf(a[p], b[q], c[p][q]);
    }
    float s[8];
    #pragma unroll
    for (int p = 0; p < 8; p++) {
        s[p] = 0.0f;
        #pragma unroll
        for (int q = 0; q < 8; q++) s[p] += __expf(c[p][q] * (1.0f / TAU));
    }
    #pragma unroll
    for (int m = 1; m < 16; m <<= 1)
        #pragma unroll
        for (int p = 0; p < 8; p++) s[p] += __shfl_xor(s[p], m, 64);
    if (tx == 0) {
        #pragma unroll
        for (int p = 0; p < 8; p++)
            rowsum_p[(size_t)jt * BATCH + i0 + ty * 8 + p] = s[p];
    }
}

// single block: reduce rowsum partials + ssl terms + bpr/reg partials -> loss
__global__ __launch_bounds__(256) void finalize(
        const float* __restrict__ rowsum_p, const float* __restrict__ diag,
        const float* __restrict__ pbpr, const float* __restrict__ preg,
        float* __restrict__ out) {
    __shared__ float red[3][4];
    const int t = threadIdx.x;
    float sb = 0.0f, sr = 0.0f, ss = 0.0f;
    for (int i = t; i < BATCH / 4; i += 256) { sb += pbpr[i]; sr += preg[i]; }
    for (int i = t; i < BATCH; i += 256) {
        float rs = 0.0f;
        #pragma unroll
        for (int j = 0; j < 32; j++) rs += rowsum_p[(size_t)j * BATCH + i];
        ss += logf(rs) - diag[i];
    }
    sb = wave_sum(sb); sr = wave_sum(sr); ss = wave_sum(ss);
    const int w = t >> 6;
    if ((t & 63) == 0) { red[0][w] = sb; red[1][w] = sr; red[2][w] = ss; }
    __syncthreads();
    if (t == 0) {
        float bpr_sum = red[0][0] + red[0][1] + red[0][2] + red[0][3];
        float reg_sum = red[1][0] + red[1][1] + red[1][2] + red[1][3];
        float ssl_sum = red[2][0] + red[2][1] + red[2][2] + red[2][3];
        float bpr = bpr_sum * (1.0f / BATCH);
        float reg = 0.5f * reg_sum * (1.0f / BATCH) * REG_LAMBDA;
        float ssl = ssl_sum * (1.0f / BATCH) * SSL_LAMBDA;
        out[0] = bpr + reg + ssl;
    }
}

extern "C" void kernel_launch(void* const* d_in, const int* in_sizes, int n_in,
                              void* d_out, int out_size, void* d_ws, size_t ws_size,
                              hipStream_t stream) {
    const int*   user    = (const int*)d_in[0];
    const int*   pos     = (const int*)d_in[1];
    const int*   neg     = (const int*)d_in[2];
    const int*   adj_row = (const int*)d_in[3];
    const int*   adj_col = (const int*)d_in[4];
    const float* adj_val = (const float*)d_in[5];
    const float* user_w  = (const float*)d_in[6];
    const float* item_w  = (const float*)d_in[7];
    float* out = (float*)d_out;

    // ---- workspace layout ----
    unsigned short* hA = (unsigned short*)d_ws;            // fp16 table (19.2 MB)
    unsigned short* hB = hA + (size_t)N_NODES * EMB;       // fp16 table (19.2 MB)
    float* buf1   = (float*)d_ws + (size_t)N_NODES * EMB;  // 38.4 MB arena region
    float* sel    = buf1 + (size_t)N_NODES * EMB;          // 786432 f
    float* un     = sel  + (size_t)3 * BATCH * EMB;        // 262144 f
    float* pn     = un   + (size_t)BATCH * EMB;            // 262144 f
    float* diag   = pn   + (size_t)BATCH * EMB;            // 4096 f
    float* rowsum_p = diag + BATCH;                        // 32*4096 f (512 KB)
    float* pbpr   = rowsum_p + 32 * BATCH;                 // 1024 f
    float* preg   = pbpr + 1024;                           // 1024 f
    int*   rowptr = (int*)(preg + 1024);                   // 150016 i
    int*   bucket_cursor = rowptr + 150016;                // 512 i  (memset)
    int*   bucket_base   = bucket_cursor + 512;            // 512 i
    int2*  colval = (int2*)(bucket_base + 512);            // 2.4M int2 (19.2 MB)
    int2*  arena  = (int2*)buf1;  // NB*CAP int2 = 31.95 MB <= 38.4 MB region

    hipMemsetAsync(bucket_cursor, 0, 512 * sizeof(int), stream);

    dim3 blk(256);

    // cast fp32->fp16 (all blocks) + binned counting-sort scatter (first 512)
    prep_kernel<<<CAST_BLK, blk, 0, stream>>>((const float4*)user_w,
                                              (const float4*)item_w, (uint2*)hA,
                                              adj_row, adj_col, adj_val,
                                              bucket_cursor, arena);
    bucket_scan<<<1, blk, 0, stream>>>(bucket_cursor, bucket_base, rowptr);
    bin_sort<<<NB, dim3(1024), 0, stream>>>(bucket_cursor, bucket_base, arena,
                                            rowptr, colval);

    // layers 1,2: full spmm (fp16 tables); layer 3 + e2-add: spmm_sel (stores)
    spmm_csr<<<(N_NODES + 3) / 4, blk, 0, stream>>>(rowptr, colval, hA, hB);
    spmm_csr<<<(N_NODES + 3) / 4, blk, 0, stream>>>(rowptr, colval, hB, hA);
    spmm_sel<<<(3 * BATCH + 3) / 4, blk, 0, stream>>>(rowptr, colval, user, pos,
                                                      neg, hA, sel);

    // batch_loss fuses e0 (fp32 weights) + e1 (hB) gathers with the loss math
    batch_loss<<<BATCH / 4, blk, 0, stream>>>(user, pos, neg, user_w, item_w,
                                              hB, sel, un, pn, diag, pbpr, preg);
    ssl_gemm<<<(BATCH / TS) * (BATCH / TS), blk, 0, stream>>>(un, pn, rowsum_p);
    finalize<<<1, blk, 0, stream>>>(rowsum_p, diag, pbpr, preg, out);
}

// Round 15
// 309.497 us; speedup vs baseline: 1.1277x; 1.0260x over previous
//
#include <hip/hip_runtime.h>
#include <hip/hip_fp16.h>
#include <math.h>

#define NUM_USERS 100000
#define NUM_ITEMS 50000
#define N_NODES   150000   // NUM_USERS + NUM_ITEMS
#define N_EDGES   2400000
#define HALF_E    (N_EDGES / 2)
#define EMB       64
#define BATCH     4096
#define TAU        0.2f
#define SSL_LAMBDA 0.1f
#define REG_LAMBDA 1e-4f

// ---- binned CSR build (coarse 512-row buckets; R14 LDS counting sort) ----
#define NB        293           // 293*512 = 150016 >= N_NODES
#define BROWS     512
#define CAP       13632         // item-bucket mean 12288 + 12 sigma
#define BINA_BLK  512
#define PER_BLK   ((HALF_E + BINA_BLK - 1) / BINA_BLK)   // 2344 edge-pairs
#define EBUF_CAP  (2 * PER_BLK)                          // 4688 records (37.5 KB)
#define CAST_BLK  9375          // 150000*64/4 threads / 256
#define JSPLIT    4             // ssl j-partials

// ---------- helpers ----------
__device__ __forceinline__ float wave_sum(float v) {
    #pragma unroll
    for (int m = 1; m < 64; m <<= 1) v += __shfl_xor(v, m, 64);
    return v;
}
__device__ __forceinline__ __half2 bits2h2(int b) {
    union { int i; __half2 h; } u; u.i = b; return u.h;
}
__device__ __forceinline__ int h22bits(__half2 h) {
    union { int i; __half2 h; } u; u.h = h; return u.i;
}
__device__ __forceinline__ float h2f(unsigned short s) {
    union { unsigned short s; __half h; } u; u.s = s; return __half2float(u.h);
}
__device__ __forceinline__ unsigned short f2h_bits(float x) {
    union { __half h; unsigned short s; } u; u.h = __float2half_rn(x); return u.s;
}
typedef _Float16 half8 __attribute__((ext_vector_type(8)));
typedef float f32x4 __attribute__((ext_vector_type(4)));

// ---- cast fp32 weights -> fp16 table (LDS-free: full occupancy). Also
// zero-fills bucket_cursor (replaces the memset dispatch).
__global__ __launch_bounds__(256) void cast_h0(
        const float4* __restrict__ uw4, const float4* __restrict__ iw4,
        uint2* __restrict__ h, int* __restrict__ bucket_cursor) {
    const int t = threadIdx.x;
    if (blockIdx.x < 2) bucket_cursor[blockIdx.x * 256 + t] = 0;
    size_t i = (size_t)blockIdx.x * 256 + t;
    const size_t tot = (size_t)N_NODES * EMB / 4;
    if (i >= tot) return;
    const size_t nu = (size_t)NUM_USERS * EMB / 4;
    float4 v = (i < nu) ? uw4[i] : iw4[i - nu];
    h[i] = make_uint2(h22bits(__floats2half2_rn(v.x, v.y)),
                      h22bits(__floats2half2_rn(v.z, v.w)));
}

// ================= edge binning with block-local counting sort =============
// arena record: x = col | (row%512)<<18 ; y = (bucket<<16) | half(val)
__global__ __launch_bounds__(256) void bin_scatter(
        const int* __restrict__ row, const int* __restrict__ col,
        const float* __restrict__ val,
        int* __restrict__ bucket_cursor, int2* __restrict__ arena) {
    __shared__ int hist[NB];      // counts -> local running cursor
    __shared__ int lbase[NB];     // local exclusive base
    __shared__ int delta[NB];     // arena_run_start - lbase
    __shared__ int sm[256];
    __shared__ int2 ebuf[EBUF_CAP];
    const int t = threadIdx.x;
    for (int k = t; k < NB; k += 256) hist[k] = 0;
    __syncthreads();
    const int beg = blockIdx.x * PER_BLK;
    const int end = min(beg + PER_BLK, HALF_E);
    for (int e = beg + t; e < end; e += 256) {
        int r = row[e], c = col[e];
        atomicAdd(&hist[r >> 9], 1);
        atomicAdd(&hist[c >> 9], 1);
    }
    __syncthreads();
    // local exclusive scan of NB counts (2 per thread)
    int v0 = (2 * t < NB) ? hist[2 * t] : 0;
    int v1 = (2 * t + 1 < NB) ? hist[2 * t + 1] : 0;
    int s = v0 + v1;
    sm[t] = s;
    __syncthreads();
    for (int m = 1; m < 256; m <<= 1) {
        int y = (t >= m) ? sm[t - m] : 0;
        __syncthreads();
        sm[t] += y;
        __syncthreads();
    }
    int excl = sm[t] - s;
    if (2 * t < NB) lbase[2 * t] = excl;
    if (2 * t + 1 < NB) lbase[2 * t + 1] = excl + v0;
    __syncthreads();
    for (int k = t; k < NB; k += 256) {
        int cnt = hist[k];
        int gb = cnt ? atomicAdd(&bucket_cursor[k], cnt) : 0;
        delta[k] = (k * CAP + gb) - lbase[k];
    }
    __syncthreads();
    for (int k = t; k < NB; k += 256) hist[k] = lbase[k];  // running cursor
    __syncthreads();
    for (int e = beg + t; e < end; e += 256) {
        int r = row[e], c = col[e];
        unsigned short h1 = f2h_bits(val[e]);
        unsigned short h2v = f2h_bits(val[e + HALF_E]);
        int b1 = r >> 9, b2 = c >> 9;
        int p1 = atomicAdd(&hist[b1], 1);
        int p2 = atomicAdd(&hist[b2], 1);
        ebuf[p1] = make_int2(c | ((r & 511) << 18), (b1 << 16) | h1);
        ebuf[p2] = make_int2(r | ((c & 511) << 18), (b2 << 16) | h2v);
    }
    __syncthreads();
    // linear write-out: consecutive i in a bucket -> consecutive arena slots
    const int count = 2 * (end - beg);
    for (int k = t; k < count; k += 256) {
        int2 rec = ebuf[k];
        int b = rec.y >> 16;        // bucket (9 bits, positive)
        arena[k + delta[b]] = rec;
    }
}

// exclusive scan of NB bucket counts -> global CSR base per bucket
__global__ __launch_bounds__(256) void bucket_scan(
        const int* __restrict__ bucket_cursor, int* __restrict__ bucket_base,
        int* __restrict__ rowptr) {
    __shared__ int sm[256];
    const int t = threadIdx.x;
    const int K = (NB + 255) / 256;   // 2
    int v[K], s = 0;
    #pragma unroll
    for (int j = 0; j < K; j++) {
        int idx = t * K + j;
        v[j] = (idx < NB) ? bucket_cursor[idx] : 0;
        s += v[j];
    }
    sm[t] = s;
    __syncthreads();
    for (int m = 1; m < 256; m <<= 1) {
        int y = (t >= m) ? sm[t - m] : 0;
        __syncthreads();
        sm[t] += y;
        __syncthreads();
    }
    int excl = sm[t] - s;
    #pragma unroll
    for (int j = 0; j < K; j++) {
        int idx = t * K + j;
        if (idx < NB) bucket_base[idx] = excl;
        excl += v[j];
    }
    if (t == 0) rowptr[N_NODES] = N_EDGES;
}

// ================= per-bucket counting sort -> CSR + rowptr =======
// 1024-thread blocks; two passes over the (L3-resident) arena; LDS ~3 KB.
__global__ __launch_bounds__(1024) void bin_sort(
        const int* __restrict__ bucket_cursor, const int* __restrict__ bucket_base,
        const int2* __restrict__ arena,
        int* __restrict__ rowptr, int2* __restrict__ colval) {
    __shared__ int rcnt[BROWS];
    __shared__ int sm[256];
    const int bin = blockIdx.x;
    const int t = threadIdx.x;
    const int total = bucket_cursor[bin];
    const int count = min(total, CAP);
    const int gbase = bucket_base[bin];
    if (t < BROWS) rcnt[t] = 0;
    __syncthreads();
    for (int i = t; i < count; i += 1024) {
        int rx = arena[bin * CAP + i].x >> 18;
        atomicAdd(&rcnt[rx & 511], 1);
    }
    __syncthreads();
    int v0 = 0, v1 = 0, s = 0;
    if (t < 256) {
        v0 = rcnt[2 * t]; v1 = rcnt[2 * t + 1];
        s = v0 + v1;
        sm[t] = s;
    }
    __syncthreads();
    for (int m = 1; m < 256; m <<= 1) {
        int y = (t < 256 && t >= m) ? sm[t - m] : 0;
        __syncthreads();
        if (t < 256) sm[t] += y;
        __syncthreads();
    }
    if (t < 256) {
        int excl = sm[t] - s;
        rcnt[2 * t] = excl;
        rcnt[2 * t + 1] = excl + v0;
        int r0 = bin * BROWS + 2 * t;
        if (r0 < N_NODES) rowptr[r0] = gbase + excl;
        if (r0 + 1 < N_NODES) rowptr[r0 + 1] = gbase + excl + v0;
    }
    __syncthreads();
    for (int i = t; i < count; i += 1024) {
        int2 rec = arena[bin * CAP + i];
        int pos = atomicAdd(&rcnt[(rec.x >> 18) & 511], 1);
        unsigned int hv = (unsigned int)rec.y & 0xFFFFu;
        colval[gbase + pos] = make_int2(rec.x & 0x3FFFF, (int)(hv * 0x10001u));
    }
    for (int i = count + t; i < total; i += 1024)
        colval[gbase + i] = make_int2(0, 0);
}

// ================= gather SpMM (fp16): h_next[r] = sum val*h_cur[col] ========
// wave = 8 edge-groups x 8 lanes x uint4 (16B/lane = 8 halves, 128B/row).
__global__ __launch_bounds__(256) void spmm_csr(
        const int* __restrict__ rowptr, const int2* __restrict__ colval,
        const unsigned short* __restrict__ h_cur, unsigned short* __restrict__ h_next) {
    const int t = threadIdx.x;
    const int lane = t & 63;
    const int g = lane >> 3;          // edge sub-slot 0..7
    const int l = lane & 7;           // uint4 index within row
    int r = blockIdx.x * 4 + (t >> 6);
    if (r >= N_NODES) return;
    const int beg = rowptr[r], end = rowptr[r + 1];
    __half2 ac0 = __float2half2_rn(0.0f), ac1 = ac0, ac2 = ac0, ac3 = ac0;
    int e = beg + g;
    if (e < end) {
        int2 cv = colval[e];
        uint4 x = ((const uint4*)(h_cur + (size_t)cv.x * EMB))[l];
        e += 8;
        if (e < end) {
            int2 cv2 = colval[e];
            uint4 x2 = ((const uint4*)(h_cur + (size_t)cv2.x * EMB))[l];
            for (e += 8; e < end; e += 8) {
                int2 cv3 = colval[e];
                uint4 x3 = ((const uint4*)(h_cur + (size_t)cv3.x * EMB))[l];
                __half2 vv = bits2h2(cv.y);
                ac0 = __hfma2(vv, bits2h2(x.x), ac0);
                ac1 = __hfma2(vv, bits2h2(x.y), ac1);
                ac2 = __hfma2(vv, bits2h2(x.z), ac2);
                ac3 = __hfma2(vv, bits2h2(x.w), ac3);
                cv = cv2; x = x2; cv2 = cv3; x2 = x3;
            }
            __half2 vv = bits2h2(cv.y);
            ac0 = __hfma2(vv, bits2h2(x.x), ac0);
            ac1 = __hfma2(vv, bits2h2(x.y), ac1);
            ac2 = __hfma2(vv, bits2h2(x.z), ac2);
            ac3 = __hfma2(vv, bits2h2(x.w), ac3);
            cv = cv2; x = x2;
        }
        __half2 vv = bits2h2(cv.y);
        ac0 = __hfma2(vv, bits2h2(x.x), ac0);
        ac1 = __hfma2(vv, bits2h2(x.y), ac1);
        ac2 = __hfma2(vv, bits2h2(x.z), ac2);
        ac3 = __hfma2(vv, bits2h2(x.w), ac3);
    }
    int a0 = h22bits(ac0), a1 = h22bits(ac1), a2 = h22bits(ac2), a3 = h22bits(ac3);
    #pragma unroll
    for (int m = 8; m < 64; m <<= 1) {
        a0 = h22bits(__hadd2(bits2h2(a0), bits2h2(__shfl_xor(a0, m, 64))));
        a1 = h22bits(__hadd2(bits2h2(a1), bits2h2(__shfl_xor(a1, m, 64))));
        a2 = h22bits(__hadd2(bits2h2(a2), bits2h2(__shfl_xor(a2, m, 64))));
        a3 = h22bits(__hadd2(bits2h2(a3), bits2h2(__shfl_xor(a3, m, 64))));
    }
    if (g == 0)
        ((uint4*)(h_next + (size_t)r * EMB))[l] =
            make_uint4((unsigned)a0, (unsigned)a1, (unsigned)a2, (unsigned)a3);
}

// ---- layer-3 sparsification, fused with the e2 self-row add; STORES
// sel[b] = f32(h_cur[r]) + sum_e val*h_cur[col]  (e0/e1 live in batch_loss)
__global__ __launch_bounds__(256) void spmm_sel(
        const int* __restrict__ rowptr, const int2* __restrict__ colval,
        const int* __restrict__ user, const int* __restrict__ pos,
        const int* __restrict__ neg,
        const unsigned short* __restrict__ h_cur, float* __restrict__ sel) {
    const int t = threadIdx.x;
    const int lane = t & 63;
    const int g = lane >> 3;
    const int l = lane & 7;
    int b = blockIdx.x * 4 + (t >> 6);
    if (b >= 3 * BATCH) return;
    int which = b / BATCH, bb = b - which * BATCH;
    int r = (which == 0) ? user[bb]
          : NUM_USERS + ((which == 1) ? pos[bb] : neg[bb]);
    const int beg = rowptr[r], end = rowptr[r + 1];
    __half2 ac0 = __float2half2_rn(0.0f), ac1 = ac0, ac2 = ac0, ac3 = ac0;
    int e = beg + g;
    if (e < end) {
        int2 cv = colval[e];
        uint4 x = ((const uint4*)(h_cur + (size_t)cv.x * EMB))[l];
        e += 8;
        if (e < end) {
            int2 cv2 = colval[e];
            uint4 x2 = ((const uint4*)(h_cur + (size_t)cv2.x * EMB))[l];
            for (e += 8; e < end; e += 8) {
                int2 cv3 = colval[e];
                uint4 x3 = ((const uint4*)(h_cur + (size_t)cv3.x * EMB))[l];
                __half2 vv = bits2h2(cv.y);
                ac0 = __hfma2(vv, bits2h2(x.x), ac0);
                ac1 = __hfma2(vv, bits2h2(x.y), ac1);
                ac2 = __hfma2(vv, bits2h2(x.z), ac2);
                ac3 = __hfma2(vv, bits2h2(x.w), ac3);
                cv = cv2; x = x2; cv2 = cv3; x2 = x3;
            }
            __half2 vv = bits2h2(cv.y);
            ac0 = __hfma2(vv, bits2h2(x.x), ac0);
            ac1 = __hfma2(vv, bits2h2(x.y), ac1);
            ac2 = __hfma2(vv, bits2h2(x.z), ac2);
            ac3 = __hfma2(vv, bits2h2(x.w), ac3);
            cv = cv2; x = x2;
        }
        __half2 vv = bits2h2(cv.y);
        ac0 = __hfma2(vv, bits2h2(x.x), ac0);
        ac1 = __hfma2(vv, bits2h2(x.y), ac1);
        ac2 = __hfma2(vv, bits2h2(x.z), ac2);
        ac3 = __hfma2(vv, bits2h2(x.w), ac3);
    }
    int a0 = h22bits(ac0), a1 = h22bits(ac1), a2 = h22bits(ac2), a3 = h22bits(ac3);
    #pragma unroll
    for (int m = 8; m < 64; m <<= 1) {
        a0 = h22bits(__hadd2(bits2h2(a0), bits2h2(__shfl_xor(a0, m, 64))));
        a1 = h22bits(__hadd2(bits2h2(a1), bits2h2(__shfl_xor(a1, m, 64))));
        a2 = h22bits(__hadd2(bits2h2(a2), bits2h2(__shfl_xor(a2, m, 64))));
        a3 = h22bits(__hadd2(bits2h2(a3), bits2h2(__shfl_xor(a3, m, 64))));
    }
    if (g == 0) {
        float2 f0 = __half22float2(bits2h2(a0));
        float2 f1 = __half22float2(bits2h2(a1));
        float2 f2 = __half22float2(bits2h2(a2));
        float2 f3 = __half22float2(bits2h2(a3));
        uint4 hx = ((const uint4*)(h_cur + (size_t)r * EMB))[l];  // e2 self-row
        float2 s0 = __half22float2(bits2h2((int)hx.x));
        float2 s1 = __half22float2(bits2h2((int)hx.y));
        float2 s2 = __half22float2(bits2h2((int)hx.z));
        float2 s3 = __half22float2(bits2h2((int)hx.w));
        float4* dst = (float4*)(sel + (size_t)b * EMB);
        dst[2 * l]     = make_float4(f0.x + s0.x, f0.y + s0.y, f1.x + s1.x, f1.y + s1.y);
        dst[2 * l + 1] = make_float4(f2.x + s2.x, f2.y + s2.y, f3.x + s3.x, f3.y + s3.y);
    }
}

// ---------- per-batch losses + normalized vectors (fp16 un/pn for MFMA) ----
__global__ __launch_bounds__(256) void batch_loss(
        const int* __restrict__ user, const int* __restrict__ pos,
        const int* __restrict__ neg,
        const float* __restrict__ uw, const float* __restrict__ iw,
        const unsigned short* __restrict__ h1,
        const float* __restrict__ sel,
        unsigned short* __restrict__ unh, unsigned short* __restrict__ pnh,
        float* __restrict__ diag,
        float* __restrict__ pbpr, float* __restrict__ preg) {
    __shared__ float lb[4], lr[4];
    const int t = threadIdx.x;
    const int lane = t & 63;
    const int w = t >> 6;
    int b = blockIdx.x * 4 + w;
    const float inv4 = 0.25f;  // / (GCN_LAYERS + 1)
    int nu = user[b], np = pos[b], ng = neg[b];
    float u = (uw[(size_t)nu * EMB + lane]
             + h2f(h1[(size_t)nu * EMB + lane])
             + sel[(size_t)b * EMB + lane]) * inv4;
    float p = (iw[(size_t)np * EMB + lane]
             + h2f(h1[(size_t)(NUM_USERS + np) * EMB + lane])
             + sel[(size_t)(BATCH + b) * EMB + lane]) * inv4;
    float n = (iw[(size_t)ng * EMB + lane]
             + h2f(h1[(size_t)(NUM_USERS + ng) * EMB + lane])
             + sel[(size_t)(2 * BATCH + b) * EMB + lane]) * inv4;
    float pos_s = wave_sum(u * p);
    float neg_s = wave_sum(u * n);
    float uu = wave_sum(u * u);
    float pp = wave_sum(p * p);
    float nn = wave_sum(n * n);
    float ru = rsqrtf(uu), rp = rsqrtf(pp);
    unh[(size_t)b * EMB + lane] = f2h_bits(u * ru);
    pnh[(size_t)b * EMB + lane] = f2h_bits(p * rp);
    if (lane == 0) {
        diag[b] = pos_s * ru * rp * (1.0f / TAU);
        float d = pos_s - neg_s;
        float tt = -d;
        lb[w] = fmaxf(tt, 0.0f) + log1pf(expf(-fabsf(tt)));  // softplus(-d)
        lr[w] = uu + pp + nn;
    }
    __syncthreads();
    if (t == 0) {
        pbpr[blockIdx.x] = lb[0] + lb[1] + lb[2] + lb[3];
        preg[blockIdx.x] = lr[0] + lr[1] + lr[2] + lr[3];
    }
}

// ================= SSL via MFMA (16x16x32 f16, fp32 accum) =================
// S = un . pn^T (both [row][k] fp16). Operand layout (m120-verified):
// A/B frag: elem [idx=lane&15][k=quad*8+j] = contiguous half8 load.
// C/D: row=quad*4+reg (m, un-row), col=lane&15 (n, pn-row). Each wave owns
// 16 un-rows x 1024 pn-cols (js split); rowsum via 4-bit shuffle reduce.
__global__ __launch_bounds__(256) void ssl_mfma(
        const unsigned short* __restrict__ unh, const unsigned short* __restrict__ pnh,
        float* __restrict__ rowsum_p) {
    const int t = threadIdx.x;
    const int lane = t & 63;
    const int idx = lane & 15, quad = lane >> 4;
    int job = blockIdx.x * 4 + (t >> 6);     // 1024 jobs = 256 it x 4 js
    int it = job & 255, js = job >> 8;
    const int i0 = it * 16;
    half8 a0 = *(const half8*)(unh + (size_t)(i0 + idx) * EMB + quad * 8);
    half8 a1 = *(const half8*)(unh + (size_t)(i0 + idx) * EMB + 32 + quad * 8);
    float rs0 = 0.0f, rs1 = 0.0f, rs2 = 0.0f, rs3 = 0.0f;
    for (int jt = 0; jt < 64; jt++) {
        int j0 = js * 1024 + jt * 16;
        half8 b0 = *(const half8*)(pnh + (size_t)(j0 + idx) * EMB + quad * 8);
        half8 b1 = *(const half8*)(pnh + (size_t)(j0 + idx) * EMB + 32 + quad * 8);
        f32x4 c = {0.0f, 0.0f, 0.0f, 0.0f};
        c = __builtin_amdgcn_mfma_f32_16x16x32_f16(a0, b0, c, 0, 0, 0);
        c = __builtin_amdgcn_mfma_f32_16x16x32_f16(a1, b1, c, 0, 0, 0);
        rs0 += __expf(c[0] * (1.0f / TAU));
        rs1 += __expf(c[1] * (1.0f / TAU));
        rs2 += __expf(c[2] * (1.0f / TAU));
        rs3 += __expf(c[3] * (1.0f / TAU));
    }
    #pragma unroll
    for (int m = 1; m < 16; m <<= 1) {
        rs0 += __shfl_xor(rs0, m, 64);
        rs1 += __shfl_xor(rs1, m, 64);
        rs2 += __shfl_xor(rs2, m, 64);
        rs3 += __shfl_xor(rs3, m, 64);
    }
    if (idx == 0) {
        float* dst = rowsum_p + (size_t)js * BATCH + i0 + quad * 4;
        dst[0] = rs0; dst[1] = rs1; dst[2] = rs2; dst[3] = rs3;
    }
}

// single block: reduce rowsum partials + ssl terms + bpr/reg partials -> loss
__global__ __launch_bounds__(256) void finalize(
        const float* __restrict__ rowsum_p, const float* __restrict__ diag,
        const float* __restrict__ pbpr, const float* __restrict__ preg,
        float* __restrict__ out) {
    __shared__ float red[3][4];
    const int t = threadIdx.x;
    float sb = 0.0f, sr = 0.0f, ss = 0.0f;
    for (int i = t; i < BATCH / 4; i += 256) { sb += pbpr[i]; sr += preg[i]; }
    for (int i = t; i < BATCH; i += 256) {
        float rs = 0.0f;
        #pragma unroll
        for (int j = 0; j < JSPLIT; j++) rs += rowsum_p[(size_t)j * BATCH + i];
        ss += logf(rs) - diag[i];
    }
    sb = wave_sum(sb); sr = wave_sum(sr); ss = wave_sum(ss);
    const int w = t >> 6;
    if ((t & 63) == 0) { red[0][w] = sb; red[1][w] = sr; red[2][w] = ss; }
    __syncthreads();
    if (t == 0) {
        float bpr_sum = red[0][0] + red[0][1] + red[0][2] + red[0][3];
        float reg_sum = red[1][0] + red[1][1] + red[1][2] + red[1][3];
        float ssl_sum = red[2][0] + red[2][1] + red[2][2] + red[2][3];
        float bpr = bpr_sum * (1.0f / BATCH);
        float reg = 0.5f * reg_sum * (1.0f / BATCH) * REG_LAMBDA;
        float ssl = ssl_sum * (1.0f / BATCH) * SSL_LAMBDA;
        out[0] = bpr + reg + ssl;
    }
}

extern "C" void kernel_launch(void* const* d_in, const int* in_sizes, int n_in,
                              void* d_out, int out_size, void* d_ws, size_t ws_size,
                              hipStream_t stream) {
    const int*   user    = (const int*)d_in[0];
    const int*   pos     = (const int*)d_in[1];
    const int*   neg     = (const int*)d_in[2];
    const int*   adj_row = (const int*)d_in[3];
    const int*   adj_col = (const int*)d_in[4];
    const float* adj_val = (const float*)d_in[5];
    const float* user_w  = (const float*)d_in[6];
    const float* item_w  = (const float*)d_in[7];
    float* out = (float*)d_out;

    // ---- workspace layout ----
    unsigned short* hA = (unsigned short*)d_ws;            // fp16 table (19.2 MB)
    unsigned short* hB = hA + (size_t)N_NODES * EMB;       // fp16 table (19.2 MB)
    float* buf1   = (float*)d_ws + (size_t)N_NODES * EMB;  // 38.4 MB arena region
    float* sel    = buf1 + (size_t)N_NODES * EMB;          // 786432 f
    unsigned short* unh = (unsigned short*)(sel + (size_t)3 * BATCH * EMB); // 512KB
    unsigned short* pnh = unh + (size_t)BATCH * EMB;       // 512 KB
    float* diag   = (float*)(pnh + (size_t)BATCH * EMB);   // 4096 f
    float* rowsum_p = diag + BATCH;                        // 4*4096 f
    float* pbpr   = rowsum_p + JSPLIT * BATCH;             // 1024 f
    float* preg   = pbpr + 1024;                           // 1024 f
    int*   rowptr = (int*)(preg + 1024);                   // 150016 i
    int*   bucket_cursor = rowptr + 150016;                // 512 i
    int*   bucket_base   = bucket_cursor + 512;            // 512 i
    int2*  colval = (int2*)(bucket_base + 512);            // 2.4M int2 (19.2 MB)
    int2*  arena  = (int2*)buf1;  // NB*CAP int2 = 31.95 MB <= 38.4 MB region

    dim3 blk(256);

    // fp32->fp16 cast (LDS-free) + bucket_cursor zero-fill
    cast_h0<<<CAST_BLK, blk, 0, stream>>>((const float4*)user_w,
                                          (const float4*)item_w, (uint2*)hA,
                                          bucket_cursor);
    // binned counting-sort scatter (512 blocks, 42 KB LDS each)
    bin_scatter<<<BINA_BLK, blk, 0, stream>>>(adj_row, adj_col, adj_val,
                                              bucket_cursor, arena);
    bucket_scan<<<1, blk, 0, stream>>>(bucket_cursor, bucket_base, rowptr);
    bin_sort<<<NB, dim3(1024), 0, stream>>>(bucket_cursor, bucket_base, arena,
                                            rowptr, colval);

    // layers 1,2: full spmm (fp16 tables); layer 3 + e2-add: spmm_sel (stores)
    spmm_csr<<<(N_NODES + 3) / 4, blk, 0, stream>>>(rowptr, colval, hA, hB);
    spmm_csr<<<(N_NODES + 3) / 4, blk, 0, stream>>>(rowptr, colval, hB, hA);
    spmm_sel<<<(3 * BATCH + 3) / 4, blk, 0, stream>>>(rowptr, colval, user, pos,
                                                      neg, hA, sel);

    // batch_loss fuses e0 (fp32 weights) + e1 (hB) gathers with the loss math
    batch_loss<<<BATCH / 4, blk, 0, stream>>>(user, pos, neg, user_w, item_w,
                                              hB, sel, unh, pnh, diag, pbpr, preg);
    ssl_mfma<<<256, blk, 0, stream>>>(unh, pnh, rowsum_p);
    finalize<<<1, blk, 0, stream>>>(rowsum_p, diag, pbpr, preg, out);
}